// Round 12
// baseline (626.630 us; speedup 1.0000x reference)
//
#include <hip/hip_runtime.h>
#include <stdint.h>

// ---------------- constants ----------------
#define N_NODES 200000
#define DIM     128
#define N_EDGES 1024
#define NNZ_C   1600000
#define NT64    3125         // N_NODES / 64 exactly (64-row gemm tiles)

// CSR-build binning
#define NBLK   250           // histogram/scatter blocks
#define CHUNK  6400          // NNZ / NBLK
#define ITERS  25            // CHUNK / 256
#define NCB    196           // coarse node buckets of 1024 nodes

// node_gather: LDS-staged indices, 8-deep row pipeline
#define NG_BLOCKS 2000
#define NG_WAVES  (NG_BLOCKS*4)   // 8000 waves
#define NG_K      25              // nodes per wave: 8000*25 = 200000 exactly
#define NG_STAGE  512             // staged visits per wave (P(exceed) ~ 0; guarded)

typedef __attribute__((ext_vector_type(8))) short short8;   // 8 bf16 (4 VGPRs)
typedef __attribute__((ext_vector_type(4))) float f32x4;

__device__ __forceinline__ float u2f(uint32_t u){ union{uint32_t u;float f;} x; x.u=u; return x.f; }
__device__ __forceinline__ uint32_t f2u(float f){ union{uint32_t u;float f;} x; x.f=f; return x.u; }
__device__ __forceinline__ unsigned short f2bf(float f){
  uint32_t u = f2u(f);
  u += 0x7fffu + ((u >> 16) & 1u);      // RNE
  return (unsigned short)(u >> 16);
}
// fast sigmoid: v_exp_f32 + v_rcp_f32 (~1 ulp each; invisible under bf16 rounding)
__device__ __forceinline__ float fsig(float x){
  float e = __builtin_amdgcn_exp2f(x * -1.44269504088896340736f);
  return __builtin_amdgcn_rcpf(1.f + e);
}

// ---------------- weight prep ----------------
// Branch-merged: time-block out = relu(x@(W1+W3) + (b1+b3) + sigmoid(x@W2+b2)).
// Wt layout [5][2][128n][128k]: j=0 -> bf16(W1+W3), j=1 -> bf16(W2).
__global__ void prep_tb_w(const float* __restrict__ W, short* __restrict__ Wt){
  int i = blockIdx.x*256 + threadIdx.x;
  if (i >= 5*256*128) return;
  int k   = i & 127;
  int col = (i >> 7) & 255;
  int s   = i >> 15;
  int j = col >> 7, n = col & 127;
  float v;
  if (j == 0)
    v = W[((s*3 + 0)*128 + k)*128 + n] + W[((s*3 + 2)*128 + k)*128 + n];
  else
    v = W[((s*3 + 1)*128 + k)*128 + n];
  Wt[i] = (short)f2bf(v);
}
// hgW fp32 transposed: Wtf[g][n][k] = W[g][k][n]
__global__ void prep_hg_wf(const float* __restrict__ W, float* __restrict__ Wtf){
  int i = blockIdx.x*256 + threadIdx.x;
  if (i >= 2*128*128) return;
  int k = i & 127;
  int n = (i >> 7) & 127;
  int g = i >> 14;
  Wtf[i] = W[(g*128 + k)*128 + n];
}

// ---------------- CSR build: deterministic binned counting sort ----------------
__global__ __launch_bounds__(256) void hist_kernel(
    const int* __restrict__ nidx, const int* __restrict__ eidx,
    int* __restrict__ ebh, int* __restrict__ nbh)
{
  __shared__ int eh[N_EDGES];
  __shared__ int nh[NCB];
  int tid = threadIdx.x, blk = blockIdx.x;
  #pragma unroll
  for (int l = tid; l < N_EDGES; l += 256) eh[l] = 0;
  for (int l = tid; l < NCB; l += 256) nh[l] = 0;
  __syncthreads();
  int base = blk*CHUNK;
  for (int it = 0; it < ITERS; it++){
    int i = base + it*256 + tid;
    atomicAdd(&eh[eidx[i]], 1);
    atomicAdd(&nh[nidx[i] >> 10], 1);
  }
  __syncthreads();
  for (int l = tid; l < N_EDGES; l += 256) ebh[blk*N_EDGES + l] = eh[l];
  for (int l = tid; l < NCB; l += 256) nbh[blk*NCB + l] = nh[l];
}

// merged scan: block 0 = edge scan (1024 threads), block 1 = node-bucket scan
__global__ __launch_bounds__(1024) void scan_kernel(
    int* __restrict__ ebh, int* __restrict__ eoff,
    int* __restrict__ nbh, int* __restrict__ cbase)
{
  __shared__ int sc[1024];
  int tid = threadIdx.x;
  if (blockIdx.x == 0){
    int e = tid;
    int total = 0;
    #pragma unroll 10
    for (int b = 0; b < NBLK; b++){
      int idx = b*N_EDGES + e;
      int t = ebh[idx];
      ebh[idx] = total;
      total += t;
    }
    sc[e] = total; __syncthreads();
    for (int off=1; off<1024; off<<=1){
      int v = (e >= off) ? sc[e-off] : 0;
      __syncthreads();
      sc[e] += v;
      __syncthreads();
    }
    int base = sc[e] - total;   // exclusive
    eoff[e] = base;
    if (e == 1023) eoff[1024] = sc[1023];
    #pragma unroll 10
    for (int b = 0; b < NBLK; b++) ebh[b*N_EDGES + e] += base;
  } else {
    int c = tid;
    int total = 0;
    if (c < NCB){
      #pragma unroll 10
      for (int b = 0; b < NBLK; b++){
        int idx = b*NCB + c;
        int t = nbh[idx];
        nbh[idx] = total;
        total += t;
      }
    }
    if (c < 256) sc[c] = (c < NCB) ? total : 0;
    __syncthreads();
    for (int off=1; off<256; off<<=1){
      int v = (c < 256 && c >= off) ? sc[c-off] : 0;
      __syncthreads();
      if (c < 256) sc[c] += v;
      __syncthreads();
    }
    if (c < NCB){
      int base = sc[c] - total;
      cbase[c] = base;
      if (c == NCB-1) cbase[NCB] = sc[c];
      #pragma unroll 10
      for (int b = 0; b < NBLK; b++) nbh[b*NCB + c] += base;
    }
  }
}

__global__ __launch_bounds__(256) void scatter_kernel(
    const int* __restrict__ nidx, const int* __restrict__ eidx,
    const int* __restrict__ ebh, const int* __restrict__ nbh,
    int* __restrict__ enodes, uint32_t* __restrict__ pairs)
{
  __shared__ int cure[N_EDGES];
  __shared__ int curn[NCB];
  int tid = threadIdx.x, blk = blockIdx.x;
  for (int l = tid; l < N_EDGES; l += 256) cure[l] = ebh[blk*N_EDGES + l];
  for (int l = tid; l < NCB; l += 256)     curn[l] = nbh[blk*NCB + l];
  __syncthreads();
  int base = blk*CHUNK;
  for (int it = 0; it < ITERS; it++){
    int i = base + it*256 + tid;
    int v = nidx[i], e = eidx[i];
    int pe = atomicAdd(&cure[e], 1);
    enodes[pe] = v;
    int pn = atomicAdd(&curn[v >> 10], 1);
    pairs[pn] = ((uint32_t)v << 10) | (uint32_t)e;
  }
}

__global__ __launch_bounds__(256) void node_build_kernel(
    const uint32_t* __restrict__ pairs, const int* __restrict__ cbase,
    int* __restrict__ noff, int* __restrict__ nedges)
{
  __shared__ int cnt[1024];
  __shared__ int off[1024];
  __shared__ int part[256];
  int tid = threadIdx.x, c = blockIdx.x;
  int n0 = c << 10;
  int nloc = min(1024, N_NODES - n0);
  int s = cbase[c], e = cbase[c+1];
  #pragma unroll
  for (int l = tid; l < 1024; l += 256) cnt[l] = 0;
  __syncthreads();
  for (int i = s + tid; i < e; i += 256)
    atomicAdd(&cnt[(pairs[i] >> 10) & 1023], 1);
  __syncthreads();
  int c0 = cnt[tid*4], c1 = cnt[tid*4+1], c2 = cnt[tid*4+2], c3 = cnt[tid*4+3];
  int sum = c0+c1+c2+c3;
  part[tid] = sum; __syncthreads();
  for (int o=1; o<256; o<<=1){
    int v = (tid >= o) ? part[tid-o] : 0;
    __syncthreads();
    part[tid] += v;
    __syncthreads();
  }
  int pb = part[tid] - sum;
  off[tid*4]   = pb;
  off[tid*4+1] = pb + c0;
  off[tid*4+2] = pb + c0 + c1;
  off[tid*4+3] = pb + c0 + c1 + c2;
  __syncthreads();
  for (int l = tid; l < nloc; l += 256) noff[n0 + l] = s + off[l];
  if (c == 0 && tid == 0) noff[N_NODES] = NNZ_C;
  __syncthreads();
  for (int i = s + tid; i < e; i += 256){
    uint32_t p = pairs[i];
    int local = (p >> 10) & 1023;
    int pos = s + atomicAdd(&off[local], 1);
    nedges[pos] = (int)((p & 1023) << 8);   // BYTE offset of edge row in mbf (256 B rows)
  }
}

// ---------------- GEMM: [N,128] @ [128, 2*128] (branch-merged), MFMA 16x16x32 ----
// 512 threads = 8 waves; wave w owns 16 output channels for both branches.
// LDS DOUBLE-BUFFER, ONE barrier per tile: a wave writing buf[p^1] at iter i+1 has
// passed iter i's barrier, which (program order) follows every wave's iter i-1
// compute from buf[p^1] -> no WAR race. Halves barrier-drain stalls vs r11.
// OUT_MODE: 0 = bf16, 1 = f32, 2 = fp8(e4m3)
template<bool IN_F32, int OUT_MODE>
__global__ __launch_bounds__(512, 6) void gemm_kernel(
    const void* __restrict__ in, void* __restrict__ out,
    const short* __restrict__ Wt, const float* __restrict__ bias)
{
  __shared__ short Atile[2][64][136];
  const int tid  = threadIdx.x;
  const int lane = tid & 63;
  const int w    = tid >> 6;          // 0..7
  const int l15  = lane & 15;
  const int quad = lane >> 4;
  const int ncol = w*16 + l15;        // output channel in [0,128)

  short8 bfrag[2][4];
  #pragma unroll
  for (int j = 0; j < 2; j++){
    const short* bp = Wt + (j*128 + ncol)*128 + quad*8;
    #pragma unroll
    for (int ks = 0; ks < 4; ks++)
      bfrag[j][ks] = *(const short8*)(bp + ks*32);
  }
  float bv13 = bias[ncol] + bias[256 + ncol];
  float bv2  = bias[128 + ncol];

  const int arow = tid >> 4;          // 0..31 (rows 0-31; +32 for second half)
  const int aseg = tid & 15;          // 16-B granule within a 128-short row

  short8 pre0, pre1;
  auto loadA = [&](int t){
    int off0 = (t*64 + arow)*128 + aseg*8;
    int off1 = off0 + 32*128;
    if (IN_F32){
      const float* f = (const float*)in;
      #pragma unroll
      for (int h = 0; h < 2; h++){
        const float* fp = f + (h ? off1 : off0);
        f32x4 q0 = *(const f32x4*)fp;
        f32x4 q1 = *(const f32x4*)(fp + 4);
        short8 t0;
        #pragma unroll
        for (int u = 0; u < 4; u++){
          t0[u]   = (short)f2bf(q0[u]);
          t0[u+4] = (short)f2bf(q1[u]);
        }
        if (h) pre1 = t0; else pre0 = t0;
      }
    } else {
      pre0 = *(const short8*)((const short*)in + off0);
      pre1 = *(const short8*)((const short*)in + off1);
    }
  };

  int t = blockIdx.x;
  int p = 0;
  loadA(t);
  for (;;){
    *(short8*)&Atile[p][arow][aseg*8]      = pre0;
    *(short8*)&Atile[p][arow + 32][aseg*8] = pre1;
    __syncthreads();
    int tn = t + gridDim.x;
    if (tn < NT64) loadA(tn);

    const int base = t*64;
    #pragma unroll
    for (int rt = 0; rt < 4; rt++){
      short8 af[4];
      #pragma unroll
      for (int ks = 0; ks < 4; ks++)
        af[ks] = *(const short8*)&Atile[p][rt*16 + l15][ks*32 + quad*8];

      f32x4 acc[2];
      #pragma unroll
      for (int j = 0; j < 2; j++){
        acc[j] = (f32x4){0.f, 0.f, 0.f, 0.f};
        #pragma unroll
        for (int ks = 0; ks < 4; ks++)
          acc[j] = __builtin_amdgcn_mfma_f32_16x16x32_bf16(
              af[ks], bfrag[j][ks], acc[j], 0, 0, 0);
      }

      #pragma unroll
      for (int r = 0; r < 4; r++){
        int row = base + rt*16 + quad*4 + r;
        float sg = fsig(acc[1][r] + bv2);
        float v = acc[0][r] + bv13 + sg;
        v = fmaxf(v, 0.f);
        if (OUT_MODE == 1) ((float*)out)[row*128 + ncol] = v;
        else if (OUT_MODE == 0) ((unsigned short*)out)[row*128 + ncol] = f2bf(v);
        else {
          int pk = __builtin_amdgcn_cvt_pk_fp8_f32(v, v, 0, false);
          ((unsigned char*)out)[row*128 + ncol] = (unsigned char)(pk & 0xff);
        }
      }
    }
    if (tn >= NT64) break;
    t = tn;
    p ^= 1;
  }
}

// ---------------- edge gather + fused edge GEMM ----------------
// One block per edge. Phase 1: gather-sum fp8 rows (8 lanes x 16 B per row,
// 32 row-slots, 4-deep pipeline). Phase 2 (fused former egemm): block already
// holds s_e in LDS -> m[e] = (s_e * 1/deg) @ W directly (Wtf is L2-hot),
// packed bf16 out. Deletes the egemm dispatch + s_e global round-trip.
__device__ __forceinline__ void acc16(float* a, uint4 r){
  uint32_t w[4] = {r.x, r.y, r.z, r.w};
  #pragma unroll
  for (int q = 0; q < 4; q++){
    auto lo = __builtin_amdgcn_cvt_pk_f32_fp8(w[q], false);
    auto hi = __builtin_amdgcn_cvt_pk_f32_fp8(w[q], true);
    a[q*4+0] += lo[0]; a[q*4+1] += lo[1]; a[q*4+2] += hi[0]; a[q*4+3] += hi[1];
  }
}

__global__ __launch_bounds__(256) void edge_gather_kernel(
    const unsigned char* __restrict__ h8, const int* __restrict__ eoff,
    const int* __restrict__ enodes, const float* __restrict__ Wtf,
    uint32_t* __restrict__ mbf)
{
  int e = blockIdx.x;
  int s = eoff[e], en = eoff[e+1];
  int tid  = threadIdx.x;
  int slot = tid >> 3;          // 32 row-slots
  int ch   = tid & 7;           // 16 B per lane
  const size_t choff = (size_t)ch * 16;

  float a[16];
  #pragma unroll
  for (int j = 0; j < 16; j++) a[j] = 0.f;

  int i0 = s + slot;
  int n0 = (i0      < en) ? enodes[i0]      : -1;
  int n1 = (i0 + 32 < en) ? enodes[i0 + 32] : -1;
  int n2 = (i0 + 64 < en) ? enodes[i0 + 64] : -1;
  int n3 = (i0 + 96 < en) ? enodes[i0 + 96] : -1;

  while (i0 < en){
    int i1 = i0 + 128;
    int m0 = (i1      < en) ? enodes[i1]      : -1;
    int m1 = (i1 + 32 < en) ? enodes[i1 + 32] : -1;
    int m2 = (i1 + 64 < en) ? enodes[i1 + 64] : -1;
    int m3 = (i1 + 96 < en) ? enodes[i1 + 96] : -1;

    uint4 r0 = *(const uint4*)(h8 + (((size_t)max(n0,0)) << 7) + choff);
    uint4 r1 = *(const uint4*)(h8 + (((size_t)max(n1,0)) << 7) + choff);
    uint4 r2 = *(const uint4*)(h8 + (((size_t)max(n2,0)) << 7) + choff);
    uint4 r3 = *(const uint4*)(h8 + (((size_t)max(n3,0)) << 7) + choff);
    if (n0 < 0) r0 = make_uint4(0,0,0,0);
    if (n1 < 0) r1 = make_uint4(0,0,0,0);
    if (n2 < 0) r2 = make_uint4(0,0,0,0);
    if (n3 < 0) r3 = make_uint4(0,0,0,0);

    acc16(a, r0); acc16(a, r1); acc16(a, r2); acc16(a, r3);

    n0 = m0; n1 = m1; n2 = m2; n3 = m3;
    i0 = i1;
  }

  __shared__ float red[32][132];
  __shared__ float srow[128];
  __shared__ float sacc[128];
  #pragma unroll
  for (int j = 0; j < 16; j++) red[slot][ch*16 + j] = a[j];
  __syncthreads();
  if (tid < 128){
    float sum = 0.f;
    #pragma unroll
    for (int r = 0; r < 32; r++) sum += red[r][tid];
    srow[tid] = sum;
  }
  __syncthreads();
  int deg = en - s;
  float be = deg > 0 ? 1.f/(float)deg : 0.f;
  if (tid < 128){
    const f32x4* w4 = (const f32x4*)(Wtf + tid*128);
    float acc = 0.f;
    #pragma unroll
    for (int k = 0; k < 32; k++){
      f32x4 qv = w4[k];
      acc += qv[0]*srow[k*4] + qv[1]*srow[k*4+1] + qv[2]*srow[k*4+2] + qv[3]*srow[k*4+3];
    }
    sacc[tid] = acc * be;
  }
  __syncthreads();
  if (tid < 64){
    uint32_t lo = f2bf(sacc[2*tid]);
    uint32_t hi = f2bf(sacc[2*tid+1]);
    mbf[e*64 + tid] = (hi << 16) | lo;
  }
}

// ---------------- node gather: LDS-staged indices + 8-deep row pipeline ----------------
__global__ __launch_bounds__(256) void node_gather_kernel(
    const uint32_t* __restrict__ mbf, const int* __restrict__ noff,
    const int* __restrict__ nedges, const float* __restrict__ hb,
    uint32_t* __restrict__ outp)
{
  __shared__ int sidx[4][NG_STAGE];
  const int wslot = threadIdx.x >> 6;
  const int wid   = (blockIdx.x << 2) | wslot;
  const int lane  = threadIdx.x & 63;
  const int lane4 = lane << 2;
  const float b0 = hb[2*lane], b1 = hb[2*lane+1];
  const int v0 = wid * NG_K;

  // staged per-node end offsets: lane l holds noff[v0+1+l]
  int eArr = noff[min(v0 + 1 + lane, N_NODES)];
  int sW   = __builtin_amdgcn_readfirstlane(noff[v0]);
  int send = __builtin_amdgcn_readlane(eArr, NG_K - 1);
  int n = send - sW;

  int* myIdx = sidx[wslot];
  bool useLds = (n <= NG_STAGE);
  if (useLds){
    for (int b = lane; b < n; b += 64) myIdx[b] = nedges[sW + b];
  }
  __syncthreads();

  const char* mb = (const char*)mbf;
  if (useLds){
    int s = sW;
    for (int vr = 0; vr < NG_K; vr++){
      int e = __builtin_amdgcn_readlane(eArr, vr);
      float a0 = 0.f, a1 = 0.f;
      uint32_t rlast = 0;
      for (int i = s; i < e; i += 8){
        uint32_t r[8];
        #pragma unroll
        for (int k = 0; k < 8; k++){
          int li = min(i + k, e - 1) - sW;
          r[k] = *(const uint32_t*)(mb + (myIdx[li] + lane4));
        }
        #pragma unroll
        for (int k = 0; k < 8; k++){
          a0 += u2f(r[k] << 16);
          a1 += u2f(r[k] & 0xffff0000u);
        }
        rlast = r[7];
      }
      int d = e - s;
      float dead = (float)(((d + 7) & ~7) - d);
      a0 -= dead * u2f(rlast << 16);
      a1 -= dead * u2f(rlast & 0xffff0000u);
      float dn = (d > 0) ? 1.f/(float)d : 0.f;
      uint32_t lo = f2bf(a0*dn + b0);
      uint32_t hi = f2bf(a1*dn + b1);
      outp[((size_t)(v0 + vr) << 6) | lane] = (hi << 16) | lo;
      s = e;
    }
  } else {
    // fallback (statistically never): direct global-index path
    int s = sW;
    for (int vr = 0; vr < NG_K; vr++){
      int e = __builtin_amdgcn_readlane(eArr, vr);
      float a0 = 0.f, a1 = 0.f;
      for (int i = s; i < e; i++){
        uint32_t r = *(const uint32_t*)(mb + (nedges[i] + lane4));
        a0 += u2f(r << 16);
        a1 += u2f(r & 0xffff0000u);
      }
      int d = e - s;
      float dn = (d > 0) ? 1.f/(float)d : 0.f;
      uint32_t lo = f2bf(a0*dn + b0);
      uint32_t hi = f2bf(a1*dn + b1);
      outp[((size_t)(v0 + vr) << 6) | lane] = (hi << 16) | lo;
      s = e;
    }
  }
}

// ---------------- host launch ----------------
extern "C" void kernel_launch(void* const* d_in, const int* in_sizes, int n_in,
                              void* d_out, int out_size, void* d_ws, size_t ws_size,
                              hipStream_t stream)
{
  (void)in_sizes; (void)n_in; (void)out_size; (void)ws_size;
  const float* x   = (const float*)d_in[0];
  const float* tbW = (const float*)d_in[1];
  const float* tbb = (const float*)d_in[2];
  const float* hgW = (const float*)d_in[3];
  const float* hgb = (const float*)d_in[4];
  const int* nidx  = (const int*)d_in[6];
  const int* eidx  = (const int*)d_in[7];
  float* out = (float*)d_out;

  char* p = (char*)d_ws;
  auto alloc = [&](size_t sz){ void* r = (void*)p; p += (sz + 255) & ~(size_t)255; return r; };
  unsigned short* hA = (unsigned short*)alloc((size_t)N_NODES*DIM*2);  // 51.2 MB
  unsigned short* hB = (unsigned short*)alloc((size_t)N_NODES*DIM*2);  // 51.2 MB
  unsigned char*  h8 = (unsigned char*)alloc((size_t)N_NODES*DIM);     // 25.6 MB
  uint32_t* mbf = (uint32_t*)alloc((size_t)N_EDGES*64*4);              // 256 KB (L2-resident)
  short* WtTb = (short*)alloc((size_t)5*256*128*2);                    // merged: [5][2][128][128]
  float* Wtf  = (float*)alloc((size_t)2*128*128*4);
  int* ebh  = (int*)alloc((size_t)NBLK*N_EDGES*4);
  int* nbh  = (int*)alloc((size_t)NBLK*NCB*4);
  int* eoff = (int*)alloc((N_EDGES+1)*4);
  int* cbase= (int*)alloc((NCB+1)*4);
  int* noff = (int*)alloc((size_t)(N_NODES+1)*4);
  int* enodes = (int*)alloc((size_t)NNZ_C*4);
  int* nedges = (int*)alloc((size_t)NNZ_C*4 + 64);   // +pad
  uint32_t* pairs = (uint32_t*)h8;   // transient: consumed by node_build before h8 is written

  prep_tb_w<<<640, 256, 0, stream>>>(tbW, WtTb);
  prep_hg_wf<<<128, 256, 0, stream>>>(hgW, Wtf);

  // CSR build (deterministic, no global atomics)
  hist_kernel<<<NBLK, 256, 0, stream>>>(nidx, eidx, ebh, nbh);
  scan_kernel<<<2, 1024, 0, stream>>>(ebh, eoff, nbh, cbase);
  scatter_kernel<<<NBLK, 256, 0, stream>>>(nidx, eidx, ebh, nbh, enodes, pairs);
  node_build_kernel<<<NCB, 256, 0, stream>>>(pairs, cbase, noff, nedges);

  // TB0: x (fp32) -> h8 (fp8)
  gemm_kernel<true, 2><<<1250, 512, 0, stream>>>(x, h8, WtTb, tbb);
  // conv0: gather-sum + fused edge-GEMM -> mbf; node gather -> hA (bf16)
  edge_gather_kernel<<<N_EDGES, 256, 0, stream>>>(h8, eoff, enodes, Wtf, mbf);
  node_gather_kernel<<<NG_BLOCKS, 256, 0, stream>>>(mbf, noff, nedges, hgb, (uint32_t*)hA);
  // TB1: hA -> hB (bf16), TB2: hB -> h8 (fp8)
  gemm_kernel<false, 0><<<1250, 512, 0, stream>>>(hA, hB, WtTb + 1*32768, tbb + 1*384);
  gemm_kernel<false, 2><<<1250, 512, 0, stream>>>(hB, h8, WtTb + 2*32768, tbb + 2*384);
  // conv1
  edge_gather_kernel<<<N_EDGES, 256, 0, stream>>>(h8, eoff, enodes, Wtf + 16384, mbf);
  node_gather_kernel<<<NG_BLOCKS, 256, 0, stream>>>(mbf, noff, nedges, hgb + 128, (uint32_t*)hA);
  // TB3: hA -> hB, TB4: hB -> out (fp32)
  gemm_kernel<false, 0><<<1250, 512, 0, stream>>>(hA, hB, WtTb + 3*32768, tbb + 3*384);
  gemm_kernel<false, 1><<<1250, 512, 0, stream>>>(hB, out, WtTb + 4*32768, tbb + 4*384);
}

// Round 13
// 616.595 us; speedup vs baseline: 1.0163x; 1.0163x over previous
//
#include <hip/hip_runtime.h>
#include <stdint.h>

// ---------------- constants ----------------
#define N_NODES 200000
#define DIM     128
#define N_EDGES 1024
#define NNZ_C   1600000
#define NT64    3125         // N_NODES / 64 exactly (64-row gemm tiles)

// CSR-build binning
#define NBLK   250           // histogram/scatter blocks
#define CHUNK  6400          // NNZ / NBLK
#define ITERS  25            // CHUNK / 256
#define NCB    196           // coarse node buckets of 1024 nodes

// node_gather: LDS-staged indices, 8-deep row pipeline
#define NG_BLOCKS 2000
#define NG_WAVES  (NG_BLOCKS*4)   // 8000 waves
#define NG_K      25              // nodes per wave: 8000*25 = 200000 exactly
#define NG_STAGE  512             // staged visits per wave (P(exceed) ~ 0; guarded)

typedef __attribute__((ext_vector_type(8))) short short8;   // 8 bf16 (4 VGPRs)
typedef __attribute__((ext_vector_type(4))) float f32x4;

__device__ __forceinline__ float u2f(uint32_t u){ union{uint32_t u;float f;} x; x.u=u; return x.f; }
__device__ __forceinline__ uint32_t f2u(float f){ union{uint32_t u;float f;} x; x.f=f; return x.u; }
__device__ __forceinline__ unsigned short f2bf(float f){
  uint32_t u = f2u(f);
  u += 0x7fffu + ((u >> 16) & 1u);      // RNE
  return (unsigned short)(u >> 16);
}
// fast sigmoid: v_exp_f32 + v_rcp_f32 (~1 ulp each; invisible under bf16 rounding)
__device__ __forceinline__ float fsig(float x){
  float e = __builtin_amdgcn_exp2f(x * -1.44269504088896340736f);
  return __builtin_amdgcn_rcpf(1.f + e);
}

// ---------------- weight prep ----------------
// Branch-merged: time-block out = relu(x@(W1+W3) + (b1+b3) + sigmoid(x@W2+b2)).
// Wt layout [5][2][128n][128k]: j=0 -> bf16(W1+W3), j=1 -> bf16(W2).
__global__ void prep_tb_w(const float* __restrict__ W, short* __restrict__ Wt){
  int i = blockIdx.x*256 + threadIdx.x;
  if (i >= 5*256*128) return;
  int k   = i & 127;
  int col = (i >> 7) & 255;
  int s   = i >> 15;
  int j = col >> 7, n = col & 127;
  float v;
  if (j == 0)
    v = W[((s*3 + 0)*128 + k)*128 + n] + W[((s*3 + 2)*128 + k)*128 + n];
  else
    v = W[((s*3 + 1)*128 + k)*128 + n];
  Wt[i] = (short)f2bf(v);
}
// hgW fp32 transposed: Wtf[g][n][k] = W[g][k][n]
__global__ void prep_hg_wf(const float* __restrict__ W, float* __restrict__ Wtf){
  int i = blockIdx.x*256 + threadIdx.x;
  if (i >= 2*128*128) return;
  int k = i & 127;
  int n = (i >> 7) & 127;
  int g = i >> 14;
  Wtf[i] = W[(g*128 + k)*128 + n];
}

// ---------------- CSR build: deterministic binned counting sort ----------------
__global__ __launch_bounds__(256) void hist_kernel(
    const int* __restrict__ nidx, const int* __restrict__ eidx,
    int* __restrict__ ebh, int* __restrict__ nbh)
{
  __shared__ int eh[N_EDGES];
  __shared__ int nh[NCB];
  int tid = threadIdx.x, blk = blockIdx.x;
  #pragma unroll
  for (int l = tid; l < N_EDGES; l += 256) eh[l] = 0;
  for (int l = tid; l < NCB; l += 256) nh[l] = 0;
  __syncthreads();
  int base = blk*CHUNK;
  for (int it = 0; it < ITERS; it++){
    int i = base + it*256 + tid;
    atomicAdd(&eh[eidx[i]], 1);
    atomicAdd(&nh[nidx[i] >> 10], 1);
  }
  __syncthreads();
  for (int l = tid; l < N_EDGES; l += 256) ebh[blk*N_EDGES + l] = eh[l];
  for (int l = tid; l < NCB; l += 256) nbh[blk*NCB + l] = nh[l];
}

// merged scan: block 0 = edge scan (1024 threads), block 1 = node-bucket scan
__global__ __launch_bounds__(1024) void scan_kernel(
    int* __restrict__ ebh, int* __restrict__ eoff,
    int* __restrict__ nbh, int* __restrict__ cbase)
{
  __shared__ int sc[1024];
  int tid = threadIdx.x;
  if (blockIdx.x == 0){
    int e = tid;
    int total = 0;
    #pragma unroll 10
    for (int b = 0; b < NBLK; b++){
      int idx = b*N_EDGES + e;
      int t = ebh[idx];
      ebh[idx] = total;
      total += t;
    }
    sc[e] = total; __syncthreads();
    for (int off=1; off<1024; off<<=1){
      int v = (e >= off) ? sc[e-off] : 0;
      __syncthreads();
      sc[e] += v;
      __syncthreads();
    }
    int base = sc[e] - total;   // exclusive
    eoff[e] = base;
    if (e == 1023) eoff[1024] = sc[1023];
    #pragma unroll 10
    for (int b = 0; b < NBLK; b++) ebh[b*N_EDGES + e] += base;
  } else {
    int c = tid;
    int total = 0;
    if (c < NCB){
      #pragma unroll 10
      for (int b = 0; b < NBLK; b++){
        int idx = b*NCB + c;
        int t = nbh[idx];
        nbh[idx] = total;
        total += t;
      }
    }
    if (c < 256) sc[c] = (c < NCB) ? total : 0;
    __syncthreads();
    for (int off=1; off<256; off<<=1){
      int v = (c < 256 && c >= off) ? sc[c-off] : 0;
      __syncthreads();
      if (c < 256) sc[c] += v;
      __syncthreads();
    }
    if (c < NCB){
      int base = sc[c] - total;
      cbase[c] = base;
      if (c == NCB-1) cbase[NCB] = sc[c];
      #pragma unroll 10
      for (int b = 0; b < NBLK; b++) nbh[b*NCB + c] += base;
    }
  }
}

__global__ __launch_bounds__(256) void scatter_kernel(
    const int* __restrict__ nidx, const int* __restrict__ eidx,
    const int* __restrict__ ebh, const int* __restrict__ nbh,
    int* __restrict__ enodes, uint32_t* __restrict__ pairs)
{
  __shared__ int cure[N_EDGES];
  __shared__ int curn[NCB];
  int tid = threadIdx.x, blk = blockIdx.x;
  for (int l = tid; l < N_EDGES; l += 256) cure[l] = ebh[blk*N_EDGES + l];
  for (int l = tid; l < NCB; l += 256)     curn[l] = nbh[blk*NCB + l];
  __syncthreads();
  int base = blk*CHUNK;
  for (int it = 0; it < ITERS; it++){
    int i = base + it*256 + tid;
    int v = nidx[i], e = eidx[i];
    int pe = atomicAdd(&cure[e], 1);
    enodes[pe] = v;
    int pn = atomicAdd(&curn[v >> 10], 1);
    pairs[pn] = ((uint32_t)v << 10) | (uint32_t)e;
  }
}

__global__ __launch_bounds__(256) void node_build_kernel(
    const uint32_t* __restrict__ pairs, const int* __restrict__ cbase,
    int* __restrict__ noff, int* __restrict__ nedges)
{
  __shared__ int cnt[1024];
  __shared__ int off[1024];
  __shared__ int part[256];
  int tid = threadIdx.x, c = blockIdx.x;
  int n0 = c << 10;
  int nloc = min(1024, N_NODES - n0);
  int s = cbase[c], e = cbase[c+1];
  #pragma unroll
  for (int l = tid; l < 1024; l += 256) cnt[l] = 0;
  __syncthreads();
  for (int i = s + tid; i < e; i += 256)
    atomicAdd(&cnt[(pairs[i] >> 10) & 1023], 1);
  __syncthreads();
  int c0 = cnt[tid*4], c1 = cnt[tid*4+1], c2 = cnt[tid*4+2], c3 = cnt[tid*4+3];
  int sum = c0+c1+c2+c3;
  part[tid] = sum; __syncthreads();
  for (int o=1; o<256; o<<=1){
    int v = (tid >= o) ? part[tid-o] : 0;
    __syncthreads();
    part[tid] += v;
    __syncthreads();
  }
  int pb = part[tid] - sum;
  off[tid*4]   = pb;
  off[tid*4+1] = pb + c0;
  off[tid*4+2] = pb + c0 + c1;
  off[tid*4+3] = pb + c0 + c1 + c2;
  __syncthreads();
  for (int l = tid; l < nloc; l += 256) noff[n0 + l] = s + off[l];
  if (c == 0 && tid == 0) noff[N_NODES] = NNZ_C;
  __syncthreads();
  for (int i = s + tid; i < e; i += 256){
    uint32_t p = pairs[i];
    int local = (p >> 10) & 1023;
    int pos = s + atomicAdd(&off[local], 1);
    nedges[pos] = (int)((p & 1023) << 8);   // BYTE offset of edge row in mbf (256 B rows)
  }
}

// ---------------- GEMM: [N,128] @ [128, 2*128] (branch-merged), MFMA 16x16x32 ----
// r11 structure (proven best): single Atile, two barriers per tile, 512 threads =
// 8 waves, wave owns 16 output channels for both branches (bfrag[2][4] = 32 VGPR),
// 64-row tile, staging 2 short8/thread register-prefetched across tiles.
// OUT_MODE: 0 = bf16, 1 = f32, 2 = fp8(e4m3)
template<bool IN_F32, int OUT_MODE>
__global__ __launch_bounds__(512, 6) void gemm_kernel(
    const void* __restrict__ in, void* __restrict__ out,
    const short* __restrict__ Wt, const float* __restrict__ bias)
{
  __shared__ short Atile[64][136];
  const int tid  = threadIdx.x;
  const int lane = tid & 63;
  const int w    = tid >> 6;          // 0..7
  const int l15  = lane & 15;
  const int quad = lane >> 4;
  const int ncol = w*16 + l15;        // output channel in [0,128)

  short8 bfrag[2][4];
  #pragma unroll
  for (int j = 0; j < 2; j++){
    const short* bp = Wt + (j*128 + ncol)*128 + quad*8;
    #pragma unroll
    for (int ks = 0; ks < 4; ks++)
      bfrag[j][ks] = *(const short8*)(bp + ks*32);
  }
  float bv13 = bias[ncol] + bias[256 + ncol];
  float bv2  = bias[128 + ncol];

  const int arow = tid >> 4;          // 0..31 (rows 0-31; +32 for second half)
  const int aseg = tid & 15;          // 16-B granule within a 128-short row

  short8 pre0, pre1;
  auto loadA = [&](int t){
    int off0 = (t*64 + arow)*128 + aseg*8;
    int off1 = off0 + 32*128;
    if (IN_F32){
      const float* f = (const float*)in;
      #pragma unroll
      for (int h = 0; h < 2; h++){
        const float* fp = f + (h ? off1 : off0);
        f32x4 q0 = *(const f32x4*)fp;
        f32x4 q1 = *(const f32x4*)(fp + 4);
        short8 t0;
        #pragma unroll
        for (int u = 0; u < 4; u++){
          t0[u]   = (short)f2bf(q0[u]);
          t0[u+4] = (short)f2bf(q1[u]);
        }
        if (h) pre1 = t0; else pre0 = t0;
      }
    } else {
      pre0 = *(const short8*)((const short*)in + off0);
      pre1 = *(const short8*)((const short*)in + off1);
    }
  };

  int t = blockIdx.x;
  loadA(t);
  for (;;){
    __syncthreads();
    *(short8*)&Atile[arow][aseg*8]      = pre0;
    *(short8*)&Atile[arow + 32][aseg*8] = pre1;
    __syncthreads();
    int tn = t + gridDim.x;
    if (tn < NT64) loadA(tn);

    const int base = t*64;
    #pragma unroll
    for (int rt = 0; rt < 4; rt++){
      short8 af[4];
      #pragma unroll
      for (int ks = 0; ks < 4; ks++)
        af[ks] = *(const short8*)&Atile[rt*16 + l15][ks*32 + quad*8];

      f32x4 acc[2];
      #pragma unroll
      for (int j = 0; j < 2; j++){
        acc[j] = (f32x4){0.f, 0.f, 0.f, 0.f};
        #pragma unroll
        for (int ks = 0; ks < 4; ks++)
          acc[j] = __builtin_amdgcn_mfma_f32_16x16x32_bf16(
              af[ks], bfrag[j][ks], acc[j], 0, 0, 0);
      }

      #pragma unroll
      for (int r = 0; r < 4; r++){
        int row = base + rt*16 + quad*4 + r;
        float sg = fsig(acc[1][r] + bv2);
        float v = acc[0][r] + bv13 + sg;
        v = fmaxf(v, 0.f);
        if (OUT_MODE == 1) ((float*)out)[row*128 + ncol] = v;
        else if (OUT_MODE == 0) ((unsigned short*)out)[row*128 + ncol] = f2bf(v);
        else {
          int pk = __builtin_amdgcn_cvt_pk_fp8_f32(v, v, 0, false);
          ((unsigned char*)out)[row*128 + ncol] = (unsigned char)(pk & 0xff);
        }
      }
    }
    if (tn >= NT64) break;
    t = tn;
  }
}

// ---------------- edge gather + fused edge GEMM ----------------
// One block per edge. Phase 1: gather-sum fp8 rows (8 lanes x 16 B per row,
// 32 row-slots, 4-deep pipeline). Phase 2 (fused former egemm): block already
// holds s_e in LDS -> m[e] = (s_e * 1/deg) @ W directly (Wtf is L2-hot),
// packed bf16 out.
__device__ __forceinline__ void acc16(float* a, uint4 r){
  uint32_t w[4] = {r.x, r.y, r.z, r.w};
  #pragma unroll
  for (int q = 0; q < 4; q++){
    auto lo = __builtin_amdgcn_cvt_pk_f32_fp8(w[q], false);
    auto hi = __builtin_amdgcn_cvt_pk_f32_fp8(w[q], true);
    a[q*4+0] += lo[0]; a[q*4+1] += lo[1]; a[q*4+2] += hi[0]; a[q*4+3] += hi[1];
  }
}

__global__ __launch_bounds__(256) void edge_gather_kernel(
    const unsigned char* __restrict__ h8, const int* __restrict__ eoff,
    const int* __restrict__ enodes, const float* __restrict__ Wtf,
    uint32_t* __restrict__ mbf)
{
  int e = blockIdx.x;
  int s = eoff[e], en = eoff[e+1];
  int tid  = threadIdx.x;
  int slot = tid >> 3;          // 32 row-slots
  int ch   = tid & 7;           // 16 B per lane
  const size_t choff = (size_t)ch * 16;

  float a[16];
  #pragma unroll
  for (int j = 0; j < 16; j++) a[j] = 0.f;

  int i0 = s + slot;
  int n0 = (i0      < en) ? enodes[i0]      : -1;
  int n1 = (i0 + 32 < en) ? enodes[i0 + 32] : -1;
  int n2 = (i0 + 64 < en) ? enodes[i0 + 64] : -1;
  int n3 = (i0 + 96 < en) ? enodes[i0 + 96] : -1;

  while (i0 < en){
    int i1 = i0 + 128;
    int m0 = (i1      < en) ? enodes[i1]      : -1;
    int m1 = (i1 + 32 < en) ? enodes[i1 + 32] : -1;
    int m2 = (i1 + 64 < en) ? enodes[i1 + 64] : -1;
    int m3 = (i1 + 96 < en) ? enodes[i1 + 96] : -1;

    uint4 r0 = *(const uint4*)(h8 + (((size_t)max(n0,0)) << 7) + choff);
    uint4 r1 = *(const uint4*)(h8 + (((size_t)max(n1,0)) << 7) + choff);
    uint4 r2 = *(const uint4*)(h8 + (((size_t)max(n2,0)) << 7) + choff);
    uint4 r3 = *(const uint4*)(h8 + (((size_t)max(n3,0)) << 7) + choff);
    if (n0 < 0) r0 = make_uint4(0,0,0,0);
    if (n1 < 0) r1 = make_uint4(0,0,0,0);
    if (n2 < 0) r2 = make_uint4(0,0,0,0);
    if (n3 < 0) r3 = make_uint4(0,0,0,0);

    acc16(a, r0); acc16(a, r1); acc16(a, r2); acc16(a, r3);

    n0 = m0; n1 = m1; n2 = m2; n3 = m3;
    i0 = i1;
  }

  __shared__ float red[32][132];
  __shared__ float srow[128];
  __shared__ float sacc[128];
  #pragma unroll
  for (int j = 0; j < 16; j++) red[slot][ch*16 + j] = a[j];
  __syncthreads();
  if (tid < 128){
    float sum = 0.f;
    #pragma unroll
    for (int r = 0; r < 32; r++) sum += red[r][tid];
    srow[tid] = sum;
  }
  __syncthreads();
  int deg = en - s;
  float be = deg > 0 ? 1.f/(float)deg : 0.f;
  if (tid < 128){
    const f32x4* w4 = (const f32x4*)(Wtf + tid*128);
    float acc = 0.f;
    #pragma unroll
    for (int k = 0; k < 32; k++){
      f32x4 qv = w4[k];
      acc += qv[0]*srow[k*4] + qv[1]*srow[k*4+1] + qv[2]*srow[k*4+2] + qv[3]*srow[k*4+3];
    }
    sacc[tid] = acc * be;
  }
  __syncthreads();
  if (tid < 64){
    uint32_t lo = f2bf(sacc[2*tid]);
    uint32_t hi = f2bf(sacc[2*tid+1]);
    mbf[e*64 + tid] = (hi << 16) | lo;
  }
}

// ---------------- node gather: LDS-staged indices + 8-deep row pipeline ----------------
__global__ __launch_bounds__(256) void node_gather_kernel(
    const uint32_t* __restrict__ mbf, const int* __restrict__ noff,
    const int* __restrict__ nedges, const float* __restrict__ hb,
    uint32_t* __restrict__ outp)
{
  __shared__ int sidx[4][NG_STAGE];
  const int wslot = threadIdx.x >> 6;
  const int wid   = (blockIdx.x << 2) | wslot;
  const int lane  = threadIdx.x & 63;
  const int lane4 = lane << 2;
  const float b0 = hb[2*lane], b1 = hb[2*lane+1];
  const int v0 = wid * NG_K;

  // staged per-node end offsets: lane l holds noff[v0+1+l]
  int eArr = noff[min(v0 + 1 + lane, N_NODES)];
  int sW   = __builtin_amdgcn_readfirstlane(noff[v0]);
  int send = __builtin_amdgcn_readlane(eArr, NG_K - 1);
  int n = send - sW;

  int* myIdx = sidx[wslot];
  bool useLds = (n <= NG_STAGE);
  if (useLds){
    for (int b = lane; b < n; b += 64) myIdx[b] = nedges[sW + b];
  }
  __syncthreads();

  const char* mb = (const char*)mbf;
  if (useLds){
    int s = sW;
    for (int vr = 0; vr < NG_K; vr++){
      int e = __builtin_amdgcn_readlane(eArr, vr);
      float a0 = 0.f, a1 = 0.f;
      uint32_t rlast = 0;
      for (int i = s; i < e; i += 8){
        uint32_t r[8];
        #pragma unroll
        for (int k = 0; k < 8; k++){
          int li = min(i + k, e - 1) - sW;
          r[k] = *(const uint32_t*)(mb + (myIdx[li] + lane4));
        }
        #pragma unroll
        for (int k = 0; k < 8; k++){
          a0 += u2f(r[k] << 16);
          a1 += u2f(r[k] & 0xffff0000u);
        }
        rlast = r[7];
      }
      int d = e - s;
      float dead = (float)(((d + 7) & ~7) - d);
      a0 -= dead * u2f(rlast << 16);
      a1 -= dead * u2f(rlast & 0xffff0000u);
      float dn = (d > 0) ? 1.f/(float)d : 0.f;
      uint32_t lo = f2bf(a0*dn + b0);
      uint32_t hi = f2bf(a1*dn + b1);
      outp[((size_t)(v0 + vr) << 6) | lane] = (hi << 16) | lo;
      s = e;
    }
  } else {
    // fallback (statistically never): direct global-index path
    int s = sW;
    for (int vr = 0; vr < NG_K; vr++){
      int e = __builtin_amdgcn_readlane(eArr, vr);
      float a0 = 0.f, a1 = 0.f;
      for (int i = s; i < e; i++){
        uint32_t r = *(const uint32_t*)(mb + (nedges[i] + lane4));
        a0 += u2f(r << 16);
        a1 += u2f(r & 0xffff0000u);
      }
      int d = e - s;
      float dn = (d > 0) ? 1.f/(float)d : 0.f;
      uint32_t lo = f2bf(a0*dn + b0);
      uint32_t hi = f2bf(a1*dn + b1);
      outp[((size_t)(v0 + vr) << 6) | lane] = (hi << 16) | lo;
      s = e;
    }
  }
}

// ---------------- host launch ----------------
extern "C" void kernel_launch(void* const* d_in, const int* in_sizes, int n_in,
                              void* d_out, int out_size, void* d_ws, size_t ws_size,
                              hipStream_t stream)
{
  (void)in_sizes; (void)n_in; (void)out_size; (void)ws_size;
  const float* x   = (const float*)d_in[0];
  const float* tbW = (const float*)d_in[1];
  const float* tbb = (const float*)d_in[2];
  const float* hgW = (const float*)d_in[3];
  const float* hgb = (const float*)d_in[4];
  const int* nidx  = (const int*)d_in[6];
  const int* eidx  = (const int*)d_in[7];
  float* out = (float*)d_out;

  char* p = (char*)d_ws;
  auto alloc = [&](size_t sz){ void* r = (void*)p; p += (sz + 255) & ~(size_t)255; return r; };
  unsigned short* hA = (unsigned short*)alloc((size_t)N_NODES*DIM*2);  // 51.2 MB
  unsigned short* hB = (unsigned short*)alloc((size_t)N_NODES*DIM*2);  // 51.2 MB
  unsigned char*  h8 = (unsigned char*)alloc((size_t)N_NODES*DIM);     // 25.6 MB
  uint32_t* mbf = (uint32_t*)alloc((size_t)N_EDGES*64*4);              // 256 KB (L2-resident)
  short* WtTb = (short*)alloc((size_t)5*256*128*2);                    // merged: [5][2][128][128]
  float* Wtf  = (float*)alloc((size_t)2*128*128*4);
  int* ebh  = (int*)alloc((size_t)NBLK*N_EDGES*4);
  int* nbh  = (int*)alloc((size_t)NBLK*NCB*4);
  int* eoff = (int*)alloc((N_EDGES+1)*4);
  int* cbase= (int*)alloc((NCB+1)*4);
  int* noff = (int*)alloc((size_t)(N_NODES+1)*4);
  int* enodes = (int*)alloc((size_t)NNZ_C*4);
  int* nedges = (int*)alloc((size_t)NNZ_C*4 + 64);   // +pad
  uint32_t* pairs = (uint32_t*)alloc((size_t)NNZ_C*4);  // own buffer: CSR overlaps TB0's h8 write

  // second stream for the CSR build (independent of weight prep + TB0)
  static hipStream_t s2 = nullptr;
  static hipEvent_t evFork = nullptr, evCsr = nullptr;
  if (!s2){
    hipStreamCreateWithFlags(&s2, hipStreamNonBlocking);
    hipEventCreateWithFlags(&evFork, hipEventDisableTiming);
    hipEventCreateWithFlags(&evCsr, hipEventDisableTiming);
  }

  // fork: CSR chain on s2
  hipEventRecord(evFork, stream);
  hipStreamWaitEvent(s2, evFork, 0);
  hist_kernel<<<NBLK, 256, 0, s2>>>(nidx, eidx, ebh, nbh);
  scan_kernel<<<2, 1024, 0, s2>>>(ebh, eoff, nbh, cbase);
  scatter_kernel<<<NBLK, 256, 0, s2>>>(nidx, eidx, ebh, nbh, enodes, pairs);
  node_build_kernel<<<NCB, 256, 0, s2>>>(pairs, cbase, noff, nedges);
  hipEventRecord(evCsr, s2);

  // primary: weight prep + TB0 (x fp32 -> h8 fp8), overlapped with CSR build
  prep_tb_w<<<640, 256, 0, stream>>>(tbW, WtTb);
  prep_hg_wf<<<128, 256, 0, stream>>>(hgW, Wtf);
  gemm_kernel<true, 2><<<1250, 512, 0, stream>>>(x, h8, WtTb, tbb);

  // join: conv0 needs CSR + h8
  hipStreamWaitEvent(stream, evCsr, 0);
  edge_gather_kernel<<<N_EDGES, 256, 0, stream>>>(h8, eoff, enodes, Wtf, mbf);
  node_gather_kernel<<<NG_BLOCKS, 256, 0, stream>>>(mbf, noff, nedges, hgb, (uint32_t*)hA);
  // TB1: hA -> hB (bf16), TB2: hB -> h8 (fp8)
  gemm_kernel<false, 0><<<1250, 512, 0, stream>>>(hA, hB, WtTb + 1*32768, tbb + 1*384);
  gemm_kernel<false, 2><<<1250, 512, 0, stream>>>(hB, h8, WtTb + 2*32768, tbb + 2*384);
  // conv1
  edge_gather_kernel<<<N_EDGES, 256, 0, stream>>>(h8, eoff, enodes, Wtf + 16384, mbf);
  node_gather_kernel<<<NG_BLOCKS, 256, 0, stream>>>(mbf, noff, nedges, hgb + 128, (uint32_t*)hA);
  // TB3: hA -> hB, TB4: hB -> out (fp32)
  gemm_kernel<false, 0><<<1250, 512, 0, stream>>>(hA, hB, WtTb + 3*32768, tbb + 3*384);
  gemm_kernel<false, 1><<<1250, 512, 0, stream>>>(hB, out, WtTb + 4*32768, tbb + 4*384);
}